// Round 3
// baseline (815.499 us; speedup 1.0000x reference)
//
#include <hip/hip_runtime.h>
#include <math.h>

// Problem constants (from reference)
#define BATCH 16384
#define PP    208      // ids per row (26 features * 8 slots)
#define NF    26       // feature categories
#define VPF   50000u   // vocab per feature
#define EMB   32       // embed dim
#define DD    832      // NF * EMB
#define VOCAB (NF * 50000)

typedef __attribute__((ext_vector_type(8))) short short8v;   // 8 bf16 (4 VGPRs)
typedef __attribute__((ext_vector_type(4))) float float4v;   // MFMA C/D frag

static __device__ __forceinline__ ushort f32_to_bf16(float f) {
    unsigned u = __builtin_bit_cast(unsigned, f);
    unsigned r = (u + 0x7fffu + ((u >> 16) & 1u)) >> 16;   // RNE
    return (ushort)r;
}
static __device__ __forceinline__ unsigned pack_bf16x2(float lo, float hi) {
    return (unsigned)f32_to_bf16(lo) | ((unsigned)f32_to_bf16(hi) << 16);
}

// ---------------------------------------------------------------------------
// Kernel T: convert f32 table -> bf16 table (83 MB). 8 elems/thread.
// ---------------------------------------------------------------------------
__global__ __launch_bounds__(256) void prep_tbl(const float* __restrict__ table,
                                                ushort* __restrict__ tbl16) {
    const size_t i = ((size_t)blockIdx.x * 256 + threadIdx.x) * 8;
    if (i >= (size_t)VOCAB * EMB) return;
    const float4 a = *reinterpret_cast<const float4*>(table + i);
    const float4 b = *reinterpret_cast<const float4*>(table + i + 4);
    uint4 o;
    o.x = pack_bf16x2(a.x, a.y);
    o.y = pack_bf16x2(a.z, a.w);
    o.z = pack_bf16x2(b.x, b.y);
    o.w = pack_bf16x2(b.z, b.w);
    *reinterpret_cast<uint4*>(tbl16 + i) = o;
}

// ---------------------------------------------------------------------------
// Kernel P: pre-pack W0 (f32 [832][64]) -> bf16 fragment-ordered w0p:
//   w0p[(kt*64 + col)*32 + kk]  with k = kt*32 + kk
// ---------------------------------------------------------------------------
__global__ __launch_bounds__(256) void prep_w0(const float* __restrict__ W0,
                                               ushort* __restrict__ w0p) {
    const int i = blockIdx.x * 256 + threadIdx.x;
    if (i < DD * 64) {
        const int k = i >> 6, c = i & 63;
        const int kt = k >> 5, kk = k & 31;
        w0p[(kt * 64 + c) * 32 + kk] = f32_to_bf16(W0[i]);
    }
}

// ---------------------------------------------------------------------------
// Kernel A (primary): gather from bf16 table + per-category segment sum.
// One batch row per block. 16 lanes per table row (ushort2 = 2 dims/lane),
// 16 id-groups x 13 passes. All 13 loads batched in flight, then atomics.
// ---------------------------------------------------------------------------
__global__ __launch_bounds__(256, 4) void pool_kernel(const int* __restrict__ x,
                                                      const ushort* __restrict__ tbl,
                                                      ushort* __restrict__ feats) {
    __shared__ int   s_ids[PP];
    __shared__ float s_pool[DD];

    const int    tid = threadIdx.x;
    const size_t row = blockIdx.x;

    for (int i = tid; i < DD; i += 256) s_pool[i] = 0.0f;
    if (tid < PP / 4)
        reinterpret_cast<int4*>(s_ids)[tid] =
            reinterpret_cast<const int4*>(x + row * PP)[tid];
    __syncthreads();

    const int g = tid >> 4;    // id group 0..15
    const int l = tid & 15;    // dim pair: dims 2l, 2l+1

    unsigned ids[13];
#pragma unroll
    for (int p = 0; p < 13; ++p) ids[p] = (unsigned)s_ids[p * 16 + g];

    unsigned vals[13];
#pragma unroll
    for (int p = 0; p < 13; ++p)
        vals[p] = *reinterpret_cast<const unsigned*>(tbl + (size_t)ids[p] * EMB + 2 * l);

    float* pool = s_pool + 2 * l;
#pragma unroll
    for (int p = 0; p < 13; ++p) {
        const unsigned cat = ids[p] / VPF;
        const float f0 = __builtin_bit_cast(float, vals[p] << 16);
        const float f1 = __builtin_bit_cast(float, vals[p] & 0xffff0000u);
        atomicAdd(pool + cat * EMB + 0, f0);
        atomicAdd(pool + cat * EMB + 1, f1);
    }
    __syncthreads();

    if (tid < DD / 4) {
        ushort4 o;
        o.x = f32_to_bf16(s_pool[tid * 4 + 0]);
        o.y = f32_to_bf16(s_pool[tid * 4 + 1]);
        o.z = f32_to_bf16(s_pool[tid * 4 + 2]);
        o.w = f32_to_bf16(s_pool[tid * 4 + 3]);
        *reinterpret_cast<ushort4*>(feats + row * DD + tid * 4) = o;
    }
}

// ---------------------------------------------------------------------------
// Kernel A': fallback f32-table gather (if ws too small for tbl16).
// ---------------------------------------------------------------------------
__global__ __launch_bounds__(256, 4) void pool_kernel_f32(const int* __restrict__ x,
                                                          const float* __restrict__ table,
                                                          ushort* __restrict__ feats) {
    __shared__ int   s_ids[PP];
    __shared__ float s_pool[DD];

    const int    tid = threadIdx.x;
    const size_t row = blockIdx.x;

    for (int i = tid; i < DD; i += 256) s_pool[i] = 0.0f;
    if (tid < PP / 4)
        reinterpret_cast<int4*>(s_ids)[tid] =
            reinterpret_cast<const int4*>(x + row * PP)[tid];
    __syncthreads();

    const int e  = tid & 31;
    const int p0 = (tid >> 5) * 26;
    float* pool  = s_pool + e;

#pragma unroll 1
    for (int b = 0; b < 24; b += 4) {
        const unsigned id0 = (unsigned)s_ids[p0 + b + 0];
        const unsigned id1 = (unsigned)s_ids[p0 + b + 1];
        const unsigned id2 = (unsigned)s_ids[p0 + b + 2];
        const unsigned id3 = (unsigned)s_ids[p0 + b + 3];
        const float v0 = table[(size_t)id0 * EMB + e];
        const float v1 = table[(size_t)id1 * EMB + e];
        const float v2 = table[(size_t)id2 * EMB + e];
        const float v3 = table[(size_t)id3 * EMB + e];
        atomicAdd(pool + (id0 / VPF) * EMB, v0);
        atomicAdd(pool + (id1 / VPF) * EMB, v1);
        atomicAdd(pool + (id2 / VPF) * EMB, v2);
        atomicAdd(pool + (id3 / VPF) * EMB, v3);
    }
    {
        const unsigned idA = (unsigned)s_ids[p0 + 24];
        const unsigned idB = (unsigned)s_ids[p0 + 25];
        const float vA = table[(size_t)idA * EMB + e];
        const float vB = table[(size_t)idB * EMB + e];
        atomicAdd(pool + (idA / VPF) * EMB, vA);
        atomicAdd(pool + (idB / VPF) * EMB, vB);
    }
    __syncthreads();

    if (tid < DD / 4) {
        ushort4 o;
        o.x = f32_to_bf16(s_pool[tid * 4 + 0]);
        o.y = f32_to_bf16(s_pool[tid * 4 + 1]);
        o.z = f32_to_bf16(s_pool[tid * 4 + 2]);
        o.w = f32_to_bf16(s_pool[tid * 4 + 3]);
        *reinterpret_cast<ushort4*>(feats + row * DD + tid * 4) = o;
    }
}

// ---------------------------------------------------------------------------
// Kernel B: MFMA MLP, K-split. Block = 128 threads = 2 waves; each block
// owns 16 rows x 64 cols; wave w does kt = w*13 .. w*13+12, partials
// combined in LDS. Explicit a/b prefetch pipeline. Grid = 1024 blocks.
// Frag layout (empirically verified R2): A: row=lane&15, k=(lane>>4)*8+j;
// B: col=lane&15; C: row=(lane>>4)*4+reg, col=lane&15.
// ---------------------------------------------------------------------------
__global__ __launch_bounds__(128) void mlp_kernel(const ushort* __restrict__ feats,
                                                  const ushort* __restrict__ w0p,
                                                  const float* __restrict__ b0,
                                                  const float* __restrict__ W1,
                                                  const float* __restrict__ b1,
                                                  const float* __restrict__ W2,
                                                  float* __restrict__ out) {
    __shared__ float sC[16][68];
    __shared__ float sH1[16][17];
    __shared__ float sB0[64];

    const int tid   = threadIdx.x;
    const int wid   = tid >> 6;        // 0..1 k-split half
    const int lane  = tid & 63;
    const int lrow  = lane & 15;
    const int lk    = lane >> 4;
    const int brow0 = blockIdx.x * 16;

    if (tid < 64) sB0[tid] = b0[tid];

    float4v acc[4];
#pragma unroll
    for (int n = 0; n < 4; ++n) acc[n] = (float4v){0.f, 0.f, 0.f, 0.f};

    const int kt0 = wid * 13;
    const ushort* frow  = feats + (size_t)(brow0 + lrow) * DD + lk * 8;
    const ushort* wbase = w0p + lrow * 32 + lk * 8;

    short8v a_cur, a_nxt;
    short8v b_cur[4], b_nxt[4];
    a_cur = *reinterpret_cast<const short8v*>(frow + kt0 * 32);
#pragma unroll
    for (int n = 0; n < 4; ++n)
        b_cur[n] = *reinterpret_cast<const short8v*>(wbase + (size_t)(kt0 * 64 + n * 16) * 32);

#pragma unroll
    for (int i = 0; i < 13; ++i) {
        if (i < 12) {
            const int kt = kt0 + i + 1;
            a_nxt = *reinterpret_cast<const short8v*>(frow + kt * 32);
#pragma unroll
            for (int n = 0; n < 4; ++n)
                b_nxt[n] = *reinterpret_cast<const short8v*>(wbase + (size_t)(kt * 64 + n * 16) * 32);
        }
#pragma unroll
        for (int n = 0; n < 4; ++n)
            acc[n] = __builtin_amdgcn_mfma_f32_16x16x32_bf16(a_cur, b_cur[n], acc[n], 0, 0, 0);
        a_cur = a_nxt;
#pragma unroll
        for (int n = 0; n < 4; ++n) b_cur[n] = b_nxt[n];
    }

    if (wid == 0) {
#pragma unroll
        for (int n = 0; n < 4; ++n)
#pragma unroll
            for (int r = 0; r < 4; ++r)
                sC[lk * 4 + r][n * 16 + lrow] = acc[n][r];
    }
    __syncthreads();
    if (wid == 1) {
#pragma unroll
        for (int n = 0; n < 4; ++n)
#pragma unroll
            for (int r = 0; r < 4; ++r)
                sC[lk * 4 + r][n * 16 + lrow] += acc[n][r];
    }
    __syncthreads();

    {   // h1 = relu(relu(C + b0) @ W1 + b1): thread -> (row, 2 cols)
        const int r = tid >> 3, c = (tid & 7) * 2;
        float a0 = b1[c], a1 = b1[c + 1];
#pragma unroll 8
        for (int k = 0; k < 64; ++k) {
            const float h = fmaxf(sC[r][k] + sB0[k], 0.f);
            const float2 wv = *reinterpret_cast<const float2*>(W1 + k * 16 + c);
            a0 = fmaf(h, wv.x, a0);
            a1 = fmaf(h, wv.y, a1);
        }
        sH1[r][c + 0] = fmaxf(a0, 0.f);
        sH1[r][c + 1] = fmaxf(a1, 0.f);
    }
    __syncthreads();

    if (tid < 16) {
        float z = 0.f;
#pragma unroll
        for (int j = 0; j < 16; ++j) z = fmaf(sH1[tid][j], W2[j], z);
        out[brow0 + tid] = 1.f / (1.f + expf(-z));
    }
}

extern "C" void kernel_launch(void* const* d_in, const int* in_sizes, int n_in,
                              void* d_out, int out_size, void* d_ws, size_t ws_size,
                              hipStream_t stream) {
    const int*   x     = (const int*)d_in[0];
    const float* table = (const float*)d_in[1];
    const float* W0    = (const float*)d_in[2];
    const float* b0    = (const float*)d_in[3];
    const float* W1    = (const float*)d_in[4];
    const float* b1    = (const float*)d_in[5];
    const float* W2    = (const float*)d_in[6];
    float*       out   = (float*)d_out;

    ushort* feats16 = (ushort*)d_ws;                          // 27.3 MB
    ushort* w0p     = feats16 + (size_t)BATCH * DD;           // 106 KB
    ushort* tbl16   = w0p + (size_t)DD * 64;                  // 83.2 MB
    const size_t need = ((size_t)BATCH * DD + (size_t)DD * 64 + (size_t)VOCAB * EMB) * 2;

    prep_w0<<<(DD * 64 + 255) / 256, 256, 0, stream>>>(W0, w0p);

    if (ws_size >= need) {
        const int nconv = ((int)((size_t)VOCAB * EMB / 8) + 255) / 256;
        prep_tbl<<<nconv, 256, 0, stream>>>(table, tbl16);
        pool_kernel<<<BATCH, 256, 0, stream>>>(x, tbl16, feats16);
    } else {
        pool_kernel_f32<<<BATCH, 256, 0, stream>>>(x, table, feats16);
    }

    mlp_kernel<<<BATCH / 16, 128, 0, stream>>>(feats16, w0p, b0, W1, b1, W2, out);
}